// Round 3
// baseline (26.023 us; speedup 1.0000x reference)
//
#include <hip/hip_runtime.h>
#include <math.h>

// SinenetLayer: h[s,b,d] = a[d] * sum_t x[s,b,t] * sin( 2*pi*i(d)*f*(k_T[t]-tau) + phi[d] )
//   i(d) = d/4 + 1  (32 distinct harmonics), f = exp(nlf*LOG_F_STD + LOG_F_MEAN)
//
// Key identities:
//   sin(A + phi) = sinA*cos(phi) + cosA*sin(phi)       -> only 64 per-(s,b) reductions needed
//   sin(2*pi*i*ft) = sin(2*pi*i*frac(ft)), i integer   -> exact range reduction, hw v_sin usable
//
// One block per (s,b). Lane l owns (harmonic (l&31)+1, part l>>5 [0=sin,1=cos]).
// 4 waves split T=640 into 160-step chunks; LDS reduce; 128 threads write h[d].

#define S_DIM 25
#define B_DIM 64
#define T_DIM 640
#define D_DIM 128

__global__ __launch_bounds__(256) void sinenet_kernel(
    const float* __restrict__ x,    // (S*B, T)
    const float* __restrict__ nlf,  // (S*B)
    const float* __restrict__ tau,  // (S*B)
    const float* __restrict__ a,    // (D)
    const float* __restrict__ phi,  // (D)
    float* __restrict__ out)        // (S*B, D)
{
    __shared__ float lds_x[T_DIM];
    __shared__ float red[4][64];
    __shared__ float fin[64];

    const int bid  = blockIdx.x;      // flat (s*B + b)
    const int tid  = threadIdx.x;
    const int lane = tid & 63;
    const int wid  = tid >> 6;

    // stage x row into LDS (coalesced)
    for (int t = tid; t < T_DIM; t += 256)
        lds_x[t] = x[(size_t)bid * T_DIM + t];

    const float nlf_v = nlf[bid];
    const float tau_v = tau[bid];
    // match reference: f = exp(nlf*LOG_F_STD + LOG_F_MEAN), fp32
    const float f = expf(nlf_v * 0.373288f + 5.02654f);

    const float i_f     = (float)((lane & 31) + 1);          // harmonic 1..32
    const float quarter = (lane >> 5) ? 0.25f : 0.0f;        // cos = sin(+0.25 rev)
    const float T_WAV   = 1.0f / 16000.0f;

    __syncthreads();

    float acc = 0.0f;
    const int t0 = wid * (T_DIM / 4);
    #pragma unroll 4
    for (int t = t0; t < t0 + (T_DIM / 4); ++t) {
        const float xt = lds_x[t];                 // wave-uniform broadcast read
        const float kt = (float)t * T_WAV;         // == reference k_T[t]
        const float tv = kt - tau_v;
        const float ft = f * tv;                   // == reference f_t (fp32)
        const float u  = ft - floorf(ft);          // exact frac, in [0,1)
        const float p  = i_f * u + quarter;        // harmonic angle in revolutions
        const float w  = p - floorf(p);            // [0,1) -> hw v_sin domain
        acc = fmaf(xt, __builtin_amdgcn_sinf(w), acc);   // sin(2*pi*w)
    }

    // reduce the 4 waves' 64 lane-accumulators
    red[wid][lane] = acc;
    __syncthreads();
    if (wid == 0)
        fin[lane] = red[0][lane] + red[1][lane] + red[2][lane] + red[3][lane];
    __syncthreads();

    // epilogue: h[d] = a[d]*(cos(phi)*Ssum[i] + sin(phi)*Csum[i])
    if (tid < D_DIM) {
        const int   i0 = tid >> 2;        // 0-based harmonic index
        const float Ss = fin[i0];
        const float Cs = fin[32 + i0];
        const float ph = phi[tid];
        const float av = a[tid];
        const float sp = sinf(ph);
        const float cp = cosf(ph);
        out[(size_t)bid * D_DIM + tid] = av * fmaf(cp, Ss, sp * Cs);
    }
}

extern "C" void kernel_launch(void* const* d_in, const int* in_sizes, int n_in,
                              void* d_out, int out_size, void* d_ws, size_t ws_size,
                              hipStream_t stream) {
    const float* x   = (const float*)d_in[0];  // (S,B,1,T)
    const float* nlf = (const float*)d_in[1];  // (S,B,1,1)
    const float* tau = (const float*)d_in[2];  // (S,B,1,1)
    const float* a   = (const float*)d_in[3];  // (D)
    const float* phi = (const float*)d_in[4];  // (D)
    float* out = (float*)d_out;                // (S,B,D)

    const int n_sb = S_DIM * B_DIM;            // 1600 blocks
    sinenet_kernel<<<n_sb, 256, 0, stream>>>(x, nlf, tau, a, phi, out);
}

// Round 4
// 11.377 us; speedup vs baseline: 2.2874x; 2.2874x over previous
//
#include <hip/hip_runtime.h>
#include <math.h>

// SinenetLayer: h[s,b,d] = a[d] * sum_t x[s,b,t] * sin( 2*pi*i(d)*f*(k_T[t]-tau) + phi[d] )
//   i(d) = d/4 + 1  (32 distinct harmonics), f = exp(nlf*LOG_F_STD + LOG_F_MEAN)
//
// Identity 1: sin(A+phi) = sinA*cos(phi) + cosA*sin(phi)
//   -> only 64 per-(s,b) reductions (32 harmonics x {sin,cos}); D=128 is an epilogue.
// Identity 2 (NEW): angle is linear in t with constant step D = 2*pi*i*f*T_WAV, so
//   (sin,cos) advance by a fixed 2D rotation: 6 FMAs per (harmonic,t) covering BOTH
//   partial sums — no per-element transcendental, no fract.
//
// One block per (s,b). Lane l of wave w owns harmonic (l&31)+1 and t-chunk
// (w*2 + (l>>5)) of length 80. Per chunk: init (s,c) via one v_sin/v_cos pair
// (exact integer-harmonic range reduction: frac is error-free in fp32), then
// 80 rotation steps. LDS reduce 8 chunks -> 64 sums -> 128 outputs.

#define S_DIM 25
#define B_DIM 64
#define T_DIM 640
#define D_DIM 128
#define NCHUNK 8
#define CLEN (T_DIM / NCHUNK)   // 80

__global__ __launch_bounds__(256) void sinenet_kernel(
    const float* __restrict__ x,    // (S*B, T)
    const float* __restrict__ nlf,  // (S*B)
    const float* __restrict__ tau,  // (S*B)
    const float* __restrict__ a,    // (D)
    const float* __restrict__ phi,  // (D)
    float* __restrict__ out)        // (S*B, D)
{
    __shared__ float lds_x[T_DIM];
    __shared__ float red[2][NCHUNK][32];
    __shared__ float fin[64];

    const int bid   = blockIdx.x;        // flat (s*B + b)
    const int tid   = threadIdx.x;
    const int lane  = tid & 63;
    const int wid   = tid >> 6;
    const int h     = lane & 31;         // harmonic index 0..31
    const int chunk = wid * 2 + (lane >> 5);   // 0..7
    const int t0    = chunk * CLEN;

    // stage x row into LDS (coalesced)
    for (int t = tid; t < T_DIM; t += 256)
        lds_x[t] = x[(size_t)bid * T_DIM + t];

    const float tau_v = tau[bid];
    const float f     = expf(nlf[bid] * 0.373288f + 5.02654f);  // == reference f
    const float i_f   = (float)(h + 1);
    const float T_WAV = 1.0f / 16000.0f;

    // per-step rotation angle in revolutions: i*f*T_WAV (reduce mod 1, exact)
    const float dr0 = i_f * (f * T_WAV);
    const float dr  = dr0 - floorf(dr0);
    const float sD  = __builtin_amdgcn_sinf(dr);   // sin(2*pi*dr)
    const float cD  = __builtin_amdgcn_cosf(dr);

    // initial angle at t0: i * frac(f*(k_T[t0]-tau))  (integer harmonic -> exact reduce)
    const float tv0 = (float)t0 * T_WAV - tau_v;
    const float ft0 = f * tv0;
    const float u0  = ft0 - floorf(ft0);
    const float p0  = i_f * u0;
    const float w0  = p0 - floorf(p0);
    float s = __builtin_amdgcn_sinf(w0);
    float c = __builtin_amdgcn_cosf(w0);

    __syncthreads();

    // 80 rotation steps: 6 FMA-class VALU ops + 1 broadcast ds_read per step
    float acc_s = 0.0f, acc_c = 0.0f;
    const float* __restrict__ xp = &lds_x[t0];
    #pragma unroll 8
    for (int t = 0; t < CLEN; ++t) {
        const float xt = xp[t];                  // half-wave broadcast (2-way: free)
        acc_s = fmaf(xt, s, acc_s);
        acc_c = fmaf(xt, c, acc_c);
        const float s2 = fmaf(s, cD, c * sD);
        const float c2 = fmaf(c, cD, -(s * sD));
        s = s2; c = c2;
    }

    red[0][chunk][h] = acc_s;
    red[1][chunk][h] = acc_c;
    __syncthreads();

    if (tid < 64) {
        const int part = tid >> 5, hh = tid & 31;
        float v = 0.0f;
        #pragma unroll
        for (int cc = 0; cc < NCHUNK; ++cc)
            v += red[part][cc][hh];
        fin[tid] = v;                            // [0..31]=Ssum, [32..63]=Csum
    }
    __syncthreads();

    // epilogue: h[d] = a[d]*(cos(phi)*Ssum[i] + sin(phi)*Csum[i])
    if (tid < D_DIM) {
        const int   i0 = tid >> 2;
        const float Ss = fin[i0];
        const float Cs = fin[32 + i0];
        const float ph = phi[tid];
        out[(size_t)bid * D_DIM + tid] = a[tid] * fmaf(cosf(ph), Ss, sinf(ph) * Cs);
    }
}

extern "C" void kernel_launch(void* const* d_in, const int* in_sizes, int n_in,
                              void* d_out, int out_size, void* d_ws, size_t ws_size,
                              hipStream_t stream) {
    const float* x   = (const float*)d_in[0];  // (S,B,1,T)
    const float* nlf = (const float*)d_in[1];  // (S,B,1,1)
    const float* tau = (const float*)d_in[2];  // (S,B,1,1)
    const float* a   = (const float*)d_in[3];  // (D)
    const float* phi = (const float*)d_in[4];  // (D)
    float* out = (float*)d_out;                // (S,B,D)

    const int n_sb = S_DIM * B_DIM;            // 1600 blocks, one per (s,b)
    sinenet_kernel<<<n_sb, 256, 0, stream>>>(x, nlf, tau, a, phi, out);
}

// Round 5
// 9.466 us; speedup vs baseline: 2.7492x; 1.2019x over previous
//
#include <hip/hip_runtime.h>
#include <math.h>

// SinenetLayer: h[s,b,d] = a[d] * sum_t x[s,b,t] * sin( 2*pi*i(d)*f*(k_T[t]-tau) + phi[d] )
//   i(d) = d/4 + 1  (32 harmonics), f = exp(nlf*LOG_F_STD + LOG_F_MEAN)
//
// Identity 1: sin(A+phi) = sinA*cos(phi) + cosA*sin(phi)
//   -> 64 per-(s,b) reductions (32 harmonics x {sin,cos}); D=128 is an epilogue.
// Identity 2: angle is linear in t (step D = 2*pi*i*f*T_WAV) -> phasor rotation.
// Identity 3 (NEW, group-of-8): s_{t+j} = s_t*c_j + c_t*s_j with (c_j,s_j)
//   precomputed, so  sum_j x_j*s_{t+j} = s_t*P + c_t*Q,  P = sum x_j*c_j,
//   Q = sum x_j*s_j.  Per 8 samples: 14 FMA (P,Q) + 4 FMA (acc) + 4 (rotate 8D)
//   = 2.75 VALU/(harmonic,t) vs 6, and 2x ds_read_b128 instead of 8x b32.
//
// One block per (s,b). Lane l of wave w: harmonic h=(l&31)+1, t-chunk
// w*2+(l>>5) of length 80 (= 10 macro-steps of 8). LDS reduce -> 128 outputs.

#define S_DIM 25
#define B_DIM 64
#define T_DIM 640
#define D_DIM 128
#define NCHUNK 8
#define CLEN (T_DIM / NCHUNK)   // 80 = 10 * 8

__global__ __launch_bounds__(256) void sinenet_kernel(
    const float* __restrict__ x,    // (S*B, T)
    const float* __restrict__ nlf,  // (S*B)
    const float* __restrict__ tau,  // (S*B)
    const float* __restrict__ a,    // (D)
    const float* __restrict__ phi,  // (D)
    float* __restrict__ out)        // (S*B, D)
{
    __shared__ float lds_x[T_DIM];
    __shared__ float red[2][NCHUNK][32];
    __shared__ float fin[64];

    const int bid   = blockIdx.x;              // flat (s*B + b)
    const int tid   = threadIdx.x;
    const int lane  = tid & 63;
    const int wid   = tid >> 6;
    const int h     = lane & 31;               // harmonic index 0..31
    const int chunk = wid * 2 + (lane >> 5);   // 0..7
    const int t0    = chunk * CLEN;

    // stage x row into LDS, vectorized: 160 float4 loads (coalesced, 16B-aligned)
    if (tid < T_DIM / 4)
        reinterpret_cast<float4*>(lds_x)[tid] =
            reinterpret_cast<const float4*>(x + (size_t)bid * T_DIM)[tid];

    const float tau_v = tau[bid];
    const float f     = expf(nlf[bid] * 0.373288f + 5.02654f);  // == reference f
    const float i_f   = (float)(h + 1);
    const float T_WAV = 1.0f / 16000.0f;

    // per-step rotation angle in revolutions: frac(i*f*T_WAV) (exact mod-1)
    const float dr0 = i_f * (f * T_WAV);
    const float dr  = dr0 - floorf(dr0);
    const float sD  = __builtin_amdgcn_sinf(dr);   // sin(2*pi*dr)
    const float cD  = __builtin_amdgcn_cosf(dr);

    // group twiddles (c_j, s_j) = rot(j*D), j=1..7, and the macro-step rot(8D)
    const float c1 = cD,                        s1 = sD;
    const float c2 = fmaf(c1, cD, -(s1 * sD)),  s2 = fmaf(s1, cD, c1 * sD);
    const float c3 = fmaf(c2, cD, -(s2 * sD)),  s3 = fmaf(s2, cD, c2 * sD);
    const float c4 = fmaf(c3, cD, -(s3 * sD)),  s4 = fmaf(s3, cD, c3 * sD);
    const float c5 = fmaf(c4, cD, -(s4 * sD)),  s5 = fmaf(s4, cD, c4 * sD);
    const float c6 = fmaf(c5, cD, -(s5 * sD)),  s6 = fmaf(s5, cD, c5 * sD);
    const float c7 = fmaf(c6, cD, -(s6 * sD)),  s7 = fmaf(s6, cD, c6 * sD);
    const float c8 = fmaf(c7, cD, -(s7 * sD)),  s8 = fmaf(s7, cD, c7 * sD);

    // initial phasor at t0: i * frac(f*(k_T[t0]-tau))  (integer harmonic -> exact)
    const float tv0 = (float)t0 * T_WAV - tau_v;
    const float ft0 = f * tv0;
    const float u0  = ft0 - floorf(ft0);
    const float p0  = i_f * u0;
    const float w0  = p0 - floorf(p0);
    float s = __builtin_amdgcn_sinf(w0);
    float c = __builtin_amdgcn_cosf(w0);

    __syncthreads();

    // 10 macro-steps of 8 samples
    float acc_s = 0.0f, acc_c = 0.0f;
    const float4* __restrict__ xp4 = reinterpret_cast<const float4*>(&lds_x[t0]);
    #pragma unroll
    for (int m = 0; m < CLEN / 8; ++m) {
        const float4 xa = xp4[2 * m];       // broadcast b128 within half-wave
        const float4 xb = xp4[2 * m + 1];

        float P = xa.x;
        P = fmaf(xa.y, c1, P); P = fmaf(xa.z, c2, P); P = fmaf(xa.w, c3, P);
        P = fmaf(xb.x, c4, P); P = fmaf(xb.y, c5, P); P = fmaf(xb.z, c6, P);
        P = fmaf(xb.w, c7, P);

        float Q = xa.y * s1;
        Q = fmaf(xa.z, s2, Q); Q = fmaf(xa.w, s3, Q); Q = fmaf(xb.x, s4, Q);
        Q = fmaf(xb.y, s5, Q); Q = fmaf(xb.z, s6, Q); Q = fmaf(xb.w, s7, Q);

        acc_s = fmaf(s, P, acc_s); acc_s = fmaf(c, Q, acc_s);
        acc_c = fmaf(c, P, acc_c); acc_c = fmaf(-s, Q, acc_c);

        const float sn = fmaf(s, c8, c * s8);
        const float cn = fmaf(c, c8, -(s * s8));
        s = sn; c = cn;
    }

    red[0][chunk][h] = acc_s;
    red[1][chunk][h] = acc_c;
    __syncthreads();

    if (tid < 64) {
        const int part = tid >> 5, hh = tid & 31;
        float v = 0.0f;
        #pragma unroll
        for (int cc = 0; cc < NCHUNK; ++cc)
            v += red[part][cc][hh];
        fin[tid] = v;                        // [0..31]=Ssum, [32..63]=Csum
    }
    __syncthreads();

    // epilogue: h[d] = a[d]*(cos(phi)*Ssum + sin(phi)*Csum), hw sin/cos
    if (tid < D_DIM) {
        const int   i0 = tid >> 2;
        const float Ss = fin[i0];
        const float Cs = fin[32 + i0];
        float pr = phi[tid] * 0.15915494309189535f;   // phi/(2*pi)
        pr = pr - floorf(pr);
        const float sp = __builtin_amdgcn_sinf(pr);
        const float cp = __builtin_amdgcn_cosf(pr);
        out[(size_t)bid * D_DIM + tid] = a[tid] * fmaf(cp, Ss, sp * Cs);
    }
}

extern "C" void kernel_launch(void* const* d_in, const int* in_sizes, int n_in,
                              void* d_out, int out_size, void* d_ws, size_t ws_size,
                              hipStream_t stream) {
    const float* x   = (const float*)d_in[0];  // (S,B,1,T)
    const float* nlf = (const float*)d_in[1];  // (S,B,1,1)
    const float* tau = (const float*)d_in[2];  // (S,B,1,1)
    const float* a   = (const float*)d_in[3];  // (D)
    const float* phi = (const float*)d_in[4];  // (D)
    float* out = (float*)d_out;                // (S,B,D)

    const int n_sb = S_DIM * B_DIM;            // 1600 blocks, one per (s,b)
    sinenet_kernel<<<n_sb, 256, 0, stream>>>(x, nlf, tau, a, phi, out);
}